// Round 7
// baseline (484.896 us; speedup 1.0000x reference)
//
#include <hip/hip_runtime.h>
#include <math.h>

#define NNODES 50000
#define NEDGES 800000
#define NBLK 196   // ceil(50000/256)

typedef __attribute__((ext_vector_type(8))) short s16x8;
typedef __attribute__((ext_vector_type(8))) unsigned short u16x8;
typedef __attribute__((ext_vector_type(4))) unsigned short u16x4;
typedef __attribute__((ext_vector_type(4))) float f32x4;

__device__ __forceinline__ float tanh_fast(float x){
  float e = __builtin_amdgcn_exp2f(x*2.885390081777927f);   // e^(2x)
  return 1.0f - 2.0f*__builtin_amdgcn_rcpf(e+1.0f);
}
__device__ __forceinline__ float sig_fast(float x){
  float e = __builtin_amdgcn_exp2f(-1.4426950408889634f*x); // e^(-x)
  return __builtin_amdgcn_rcpf(1.0f+e);
}
__device__ __forceinline__ unsigned short f2b(float f){
  union{float f; unsigned u;} v; v.f = f;
  unsigned r = (v.u + 0x7FFFu + ((v.u>>16)&1u)) >> 16;
  return (unsigned short)r;
}
__device__ __forceinline__ float b2f(unsigned short b){
  union{unsigned u; float f;} v; v.u = ((unsigned)b)<<16; return v.f;
}

// linkpart[l][d] = bf16(bl[d] + sum_k emb_link[l][k]*Wl[k][d])
__global__ void k_linkpart(const float* __restrict__ emb_link, const float* __restrict__ Wl,
                           const float* __restrict__ bl, unsigned short* __restrict__ lp){
  int l = blockIdx.x, d = threadIdx.x;
  float acc = bl[d];
  #pragma unroll 8
  for(int k=0;k<64;k++) acc += emb_link[l*64+k]*Wl[k*128+d];
  lp[l*128+d] = f2b(acc);
}

// Fragment-major gate weights (K=512):
// Wfrag[((ks*32 + nt)*64 + l)*8 + j],  n = nt*16+(l&15), k = ks*32+(l>>4)*8+j
__global__ void k_prepw(const float* __restrict__ Wi, const float* __restrict__ Wo,
                        const float* __restrict__ Wf, const float* __restrict__ Wu,
                        unsigned short* __restrict__ Wfrag){
  int n = blockIdx.x; int k = threadIdx.x;
  const float* W = (n<128)? Wi : (n<256)? Wo : (n<384)? Wf : Wu;
  float v = W[(size_t)k*128 + (n&127)];
  int ks = k>>5, kb = (k>>3)&3, j = k&7;
  int nt = n>>4, lm = n&15;
  int l = lm + 16*kb;
  Wfrag[(size_t)(((ks*32 + nt)*64) + l)*8 + j] = f2b(v);
}

// Wcfrag: K=320 (Wc is 300 rows, zero-pad), N=128
__global__ void k_prepw_c(const float* __restrict__ Wc, unsigned short* __restrict__ Wcfrag){
  int n = blockIdx.x; int k = threadIdx.x;   // n<128, k<320
  float v = (k < 300)? Wc[(size_t)k*128 + n] : 0.f;
  int ks = k>>5, kb = (k>>3)&3, j = k&7;
  int nt = n>>4, lm = n&15;
  int l = lm + 16*kb;
  Wcfrag[(size_t)(((ks*8 + nt)*64) + l)*8 + j] = f2b(v);
}

// Wlfrag: bottom 128 rows of Wl, N=128
__global__ void k_prepw_l(const float* __restrict__ Wl, unsigned short* __restrict__ Wlfrag){
  int n = blockIdx.x; int k = threadIdx.x;   // n<128, k<128
  float v = Wl[(size_t)(64+k)*128 + n];
  int ks = k>>5, kb = (k>>3)&3, j = k&7;
  int nt = n>>4, lm = n&15;
  int l = lm + 16*kb;
  Wlfrag[(size_t)(((ks*8 + nt)*64) + l)*8 + j] = f2b(v);
}

// Fused: E1 = tanh(gather(emb_token)@Wc + bc); npart = bf16(E1 @ Wl[64:192])
__global__ __launch_bounds__(256,2) void k_ne(const int* __restrict__ i_token,
      const float* __restrict__ emb_token, const unsigned short* __restrict__ Wcfrag,
      const float* __restrict__ bc, const unsigned short* __restrict__ Wlfrag,
      unsigned short* __restrict__ npart){
  __shared__ unsigned short As[64*36];
  __shared__ unsigned short E1[64*132];
  __shared__ int rowidx[64];
  int t = threadIdx.x;
  int m0 = blockIdx.x*64;
  if(t<64){ int m=m0+t; rowidx[t]=(m<NNODES)? i_token[m]:0; }
  int w=t>>6, l=t&63, lm=l&15, kb=l>>4;
  f32x4 acc[2][4];
  #pragma unroll
  for(int c=0;c<2;c++)
    #pragma unroll
    for(int r=0;r<4;r++) acc[c][r]=(f32x4){0.f,0.f,0.f,0.f};
  int sr=t>>2, sp=t&3;
  __syncthreads();
  const float* srcrow = emb_token + (size_t)rowidx[sr]*300;
  for(int ks=0; ks<10; ks++){
    int k0 = ks*32 + sp*8;
    u16x8 v;
    #pragma unroll
    for(int j=0;j<8;j++){ int k=k0+j; v[j] = (k<300)? f2b(srcrow[k]) : (unsigned short)0; }
    if(ks) __syncthreads();
    *(u16x8*)(As + sr*36 + sp*8) = v;
    __syncthreads();
    s16x8 af[4];
    #pragma unroll
    for(int rt=0;rt<4;rt++) af[rt] = *(const s16x8*)(As + (16*rt+lm)*36 + kb*8);
    #pragma unroll
    for(int c=0;c<2;c++){
      int nt = 2*w + c;
      s16x8 bfr = *(const s16x8*)(Wcfrag + (size_t)((ks*8+nt)*64 + l)*8);
      #pragma unroll
      for(int rt=0;rt<4;rt++)
        acc[c][rt] = __builtin_amdgcn_mfma_f32_16x16x32_bf16(af[rt], bfr, acc[c][rt],0,0,0);
    }
  }
  __syncthreads();
  #pragma unroll
  for(int c=0;c<2;c++){
    int d = 16*(2*w+c) + lm;
    float vb = bc[d];
    #pragma unroll
    for(int rt=0;rt<4;rt++)
      #pragma unroll
      for(int reg=0;reg<4;reg++){
        int r = 16*rt + kb*4 + reg;
        E1[r*132 + d] = f2b(tanh_fast(acc[c][rt][reg]+vb));
      }
  }
  __syncthreads();
  f32x4 acc2[2][4];
  #pragma unroll
  for(int c=0;c<2;c++)
    #pragma unroll
    for(int r=0;r<4;r++) acc2[c][r]=(f32x4){0.f,0.f,0.f,0.f};
  #pragma unroll
  for(int ks=0; ks<4; ks++){
    s16x8 af[4];
    #pragma unroll
    for(int rt=0;rt<4;rt++) af[rt] = *(const s16x8*)(E1 + (16*rt+lm)*132 + ks*32 + kb*8);
    #pragma unroll
    for(int c=0;c<2;c++){
      int nt = 2*w + c;
      s16x8 bfr = *(const s16x8*)(Wlfrag + (size_t)((ks*8+nt)*64 + l)*8);
      #pragma unroll
      for(int rt=0;rt<4;rt++)
        acc2[c][rt] = __builtin_amdgcn_mfma_f32_16x16x32_bf16(af[rt], bfr, acc2[c][rt],0,0,0);
    }
  }
  #pragma unroll
  for(int c=0;c<2;c++){
    int d = 16*(2*w+c) + lm;
    #pragma unroll
    for(int rt=0;rt<4;rt++)
      #pragma unroll
      for(int reg=0;reg<4;reg++){
        int m = m0 + 16*rt + kb*4 + reg;
        if(m < NNODES) npart[(size_t)m*128 + d] = f2b(acc2[c][rt][reg]);
      }
  }
}

// ---------------- CSR build ----------------
__global__ void k_hist(const int* __restrict__ i_to, const int* __restrict__ i_from,
                       int* __restrict__ cnt_to, int* __restrict__ cnt_from,
                       int* __restrict__ rank_to, int* __restrict__ rank_from){
  int e = blockIdx.x*256 + threadIdx.x;
  if(e >= NEDGES) return;
  rank_to[e]   = atomicAdd(&cnt_to[i_to[e]], 1);
  rank_from[e] = atomicAdd(&cnt_from[i_from[e]], 1);
}

__global__ __launch_bounds__(256) void k_scanA(const int* __restrict__ cnt_to,
      const int* __restrict__ cnt_from, int* __restrict__ bsum){
  int b = blockIdx.x; int dir = (b >= NBLK); int bb = dir? b-NBLK : b;
  const int* cnt = dir? cnt_from : cnt_to;
  int t = threadIdx.x;
  int idx = bb*256 + t;
  int c = (idx < NNODES)? cnt[idx] : 0;
  __shared__ int red[256];
  red[t] = c; __syncthreads();
  for(int s=128;s>0;s>>=1){ if(t<s) red[t]+=red[t+s]; __syncthreads(); }
  if(t==0) bsum[b] = red[0];
}

__global__ __launch_bounds__(256) void k_scanB(const int* __restrict__ bsum, int* __restrict__ bpre){
  __shared__ int sh[256];
  int t = threadIdx.x;
  for(int dir=0; dir<2; dir++){
    sh[t] = (t < NBLK)? bsum[dir*NBLK + t] : 0;
    __syncthreads();
    for(int d=1; d<256; d<<=1){
      int v = (t>=d)? sh[t-d] : 0;
      __syncthreads();
      sh[t] += v;
      __syncthreads();
    }
    if(t < NBLK) bpre[dir*NBLK + t] = (t==0)? 0 : sh[t-1];
    __syncthreads();
  }
}

__global__ __launch_bounds__(256) void k_scanC(const int* __restrict__ cnt_to,
      const int* __restrict__ cnt_from, const int* __restrict__ bpre,
      int* __restrict__ off_to, int* __restrict__ end_to,
      int* __restrict__ off_from, int* __restrict__ end_from){
  int b = blockIdx.x; int dir = (b >= NBLK); int bb = dir? b-NBLK : b;
  const int* cnt = dir? cnt_from : cnt_to;
  int* off = dir? off_from : off_to;
  int* end = dir? end_from : end_to;
  int t = threadIdx.x;
  int idx = bb*256 + t;
  int c = (idx < NNODES)? cnt[idx] : 0;
  __shared__ int sh[256];
  sh[t] = c; __syncthreads();
  for(int d=1; d<256; d<<=1){
    int v = (t>=d)? sh[t-d] : 0;
    __syncthreads();
    sh[t] += v;
    __syncthreads();
  }
  if(idx < NNODES){
    int o = bpre[b] + ((t==0)? 0 : sh[t-1]);
    off[idx] = o;
    end[idx] = o + c;
  }
}

__global__ void k_place(const int* __restrict__ i_link, const int* __restrict__ i_from,
                        const int* __restrict__ i_to,
                        const int* __restrict__ off_to, const int* __restrict__ off_from,
                        const int* __restrict__ rank_to, const int* __restrict__ rank_from,
                        int* __restrict__ pay_to, int* __restrict__ pay_from){
  int e = blockIdx.x*256 + threadIdx.x;
  if(e >= NEDGES) return;
  int il = i_link[e], f = i_from[e], tt = i_to[e];
  pay_to[off_to[tt] + rank_to[e]]   = f  | (il<<16);
  pay_from[off_from[f] + rank_from[e]] = tt | (il<<16);
}

// ---------------- gathers (16 lanes per node, u16x8 = 16B per lane) ----------------
__global__ __launch_bounds__(256) void k_gather_xin(const int* __restrict__ off, const int* __restrict__ end,
      const int* __restrict__ pay, const unsigned short* __restrict__ lp,
      const unsigned short* __restrict__ npart, unsigned short* __restrict__ out){
  int n = blockIdx.x*16 + (threadIdx.x>>4);
  if(n >= NNODES) return;
  int c = (threadIdx.x & 15)*8;
  float acc[8];
  #pragma unroll
  for(int q=0;q<8;q++) acc[q]=0.f;
  int s = off[n], e = end[n];
  for(int j=s;j<e;j++){
    int p = pay[j];
    int src = p & 0xFFFF, il = p >> 16;
    u16x8 a = *(const u16x8*)(lp + il*128 + c);
    u16x8 b = *(const u16x8*)(npart + (size_t)src*128 + c);
    #pragma unroll
    for(int q=0;q<8;q++) acc[q] += tanh_fast(b2f(a[q])+b2f(b[q]));
  }
  u16x8 o;
  #pragma unroll
  for(int q=0;q<8;q++) o[q]=f2b(acc[q]);
  *(u16x8*)(out + (size_t)n*128 + c) = o;
}

__global__ __launch_bounds__(256) void k_gather_xout(const int* __restrict__ off, const int* __restrict__ end,
      const int* __restrict__ pay, const unsigned short* __restrict__ lp,
      const unsigned short* __restrict__ npart, unsigned short* __restrict__ out){
  int n = blockIdx.x*16 + (threadIdx.x>>4);
  if(n >= NNODES) return;
  int c = (threadIdx.x & 15)*8;
  u16x8 bb = *(const u16x8*)(npart + (size_t)n*128 + c);
  float bf[8];
  #pragma unroll
  for(int q=0;q<8;q++) bf[q]=b2f(bb[q]);
  float acc[8];
  #pragma unroll
  for(int q=0;q<8;q++) acc[q]=0.f;
  int s = off[n], e = end[n];
  for(int j=s;j<e;j++){
    int il = pay[j] >> 16;
    u16x8 a = *(const u16x8*)(lp + il*128 + c);
    #pragma unroll
    for(int q=0;q<8;q++) acc[q] += tanh_fast(b2f(a[q])+bf[q]);
  }
  u16x8 o;
  #pragma unroll
  for(int q=0;q<8;q++) o[q]=f2b(acc[q]);
  *(u16x8*)(out + (size_t)n*128 + c) = o;
}

__global__ __launch_bounds__(256) void k_gather_sum(const int* __restrict__ off, const int* __restrict__ end,
      const int* __restrict__ pay, const unsigned short* __restrict__ src, unsigned short* __restrict__ out){
  int n = blockIdx.x*16 + (threadIdx.x>>4);
  if(n >= NNODES) return;
  int c = (threadIdx.x & 15)*8;
  float acc[8];
  #pragma unroll
  for(int q=0;q<8;q++) acc[q]=0.f;
  int s = off[n], e = end[n];
  for(int j=s;j<e;j++){
    int v = pay[j] & 0xFFFF;
    u16x8 a = *(const u16x8*)(src + (size_t)v*128 + c);
    #pragma unroll
    for(int q=0;q<8;q++) acc[q] += b2f(a[q]);
  }
  u16x8 o;
  #pragma unroll
  for(int q=0;q<8;q++) o[q]=f2b(acc[q]);
  *(u16x8*)(out + (size_t)n*128 + c) = o;
}

// ---------------- fused MFMA gate GEMM + LSTM cell ----------------
// Barrier-free, LDS-free: 8 waves x (4 gates x 64 rows x 16 cols), A per-lane
// from global (L1-cached across waves), B from fragment-major Wfrag (L2).
template<int P>
__global__ __launch_bounds__(512,4) void k_gates(
    const unsigned short* __restrict__ x0, const unsigned short* __restrict__ x1,
    const unsigned short* __restrict__ x2, const unsigned short* __restrict__ x3,
    const unsigned short* __restrict__ Wfrag,
    const float* __restrict__ bi, const float* __restrict__ bo,
    const float* __restrict__ bfg, const float* __restrict__ bu,
    float* __restrict__ cbuf, unsigned short* __restrict__ h1,
    float* __restrict__ hout)
{
  int t = threadIdx.x;
  int m0 = blockIdx.x*64;
  int q = t>>6;                 // wave id = output col-tile (d/16)
  int l = t&63;
  int lm = l&15, kb = l>>4;
  f32x4 acc[4][4];              // [gate][rowtile]
  #pragma unroll
  for(int g=0;g<4;g++)
    #pragma unroll
    for(int r=0;r<4;r++) acc[g][r]=(f32x4){0.f,0.f,0.f,0.f};
  size_t aoff[4];
  #pragma unroll
  for(int rt=0;rt<4;rt++){
    int m = m0 + 16*rt + lm; if(m >= NNODES) m = NNODES-1;
    aoff[rt] = (size_t)m*128 + kb*8;
  }
  const int KSTEPS = P*4;
  #pragma unroll 4
  for(int ks=0; ks<KSTEPS; ks++){
    const unsigned short* src;
    if(P==2) src = (ks<4)? x0 : x1;
    else     src = (ks<4)? x0 : (ks<8)? x1 : (ks<12)? x2 : x3;
    int d0 = (ks&3)*32;
    s16x8 af[4];
    #pragma unroll
    for(int rt=0;rt<4;rt++)
      af[rt] = *(const s16x8*)(src + aoff[rt] + d0);
    #pragma unroll
    for(int g=0;g<4;g++){
      s16x8 bfr = *(const s16x8*)(Wfrag + (size_t)((ks*32 + 8*g + q)*64 + l)*8);
      #pragma unroll
      for(int rt=0; rt<4; rt++)
        acc[g][rt] = __builtin_amdgcn_mfma_f32_16x16x32_bf16(af[rt], bfr, acc[g][rt], 0,0,0);
    }
  }
  // epilogue: d = 16q+lm; rows m0+16rt+kb*4+reg  (C/D: col=lane&15, row=(lane>>4)*4+reg)
  int d = 16*q + lm;
  float vbi = bi[d], vbo = bo[d], vbu = bu[d];
  float vbf = (P==4)? bfg[d] : 0.f;
  #pragma unroll
  for(int rt=0; rt<4; rt++){
    #pragma unroll
    for(int reg=0; reg<4; reg++){
      int m = m0 + 16*rt + kb*4 + reg;
      if(m < NNODES){
        size_t o = (size_t)m*128 + d;
        float pi = acc[0][rt][reg] + vbi;
        float po = acc[1][rt][reg] + vbo;
        float pu = acc[3][rt][reg] + vbu;
        if(P==2){
          float c1v = sig_fast(pi)*tanh_fast(pu);
          float hv  = sig_fast(po)*tanh_fast(c1v);
          cbuf[o] = c1v;
          h1[o] = f2b(hv);
        } else {
          float pf = acc[2][rt][reg] + vbf;
          float c2 = sig_fast(pf)*cbuf[o] + sig_fast(pi)*tanh_fast(pu);
          hout[o] = sig_fast(po)*tanh_fast(c2);
        }
      }
    }
  }
}

extern "C" void kernel_launch(void* const* d_in, const int* in_sizes, int n_in,
                              void* d_out, int out_size, void* d_ws, size_t ws_size,
                              hipStream_t stream){
  const int*   i_token  = (const int*)d_in[0];
  const int*   i_link   = (const int*)d_in[1];
  const int*   i_from   = (const int*)d_in[2];
  const int*   i_to     = (const int*)d_in[3];
  const float* emb_token= (const float*)d_in[4];
  const float* emb_link = (const float*)d_in[5];
  const float* Wc = (const float*)d_in[6];  const float* bc = (const float*)d_in[7];
  const float* Wl = (const float*)d_in[8];  const float* bl = (const float*)d_in[9];
  const float* Wi = (const float*)d_in[10]; const float* bi = (const float*)d_in[11];
  const float* Wo = (const float*)d_in[12]; const float* bo = (const float*)d_in[13];
  const float* Wf = (const float*)d_in[14]; const float* bf_ = (const float*)d_in[15];
  const float* Wu = (const float*)d_in[16]; const float* bu = (const float*)d_in[17];
  float* out = (float*)d_out;

  const size_t NB = (size_t)NNODES*128;
  float* c1buf  = (float*)d_ws;
  unsigned short* npart = (unsigned short*)(c1buf + NB);
  unsigned short* xin   = npart + NB;
  unsigned short* xout  = xin + NB;
  unsigned short* hin   = xout + NB;
  unsigned short* houtb = hin + NB;
  unsigned short* h1    = houtb + NB;
  unsigned short* WgT   = h1 + NB;
  unsigned short* Wcfrag = WgT + 512*512;
  unsigned short* Wlfrag = Wcfrag + 320*128;
  unsigned short* linkpart = Wlfrag + 128*128;
  int* ia = (int*)(linkpart + 50*128);
  int* cnt_to   = ia + 0*NNODES;
  int* cnt_from = ia + 1*NNODES;
  int* off_to   = ia + 2*NNODES;
  int* end_to   = ia + 3*NNODES;
  int* off_from = ia + 4*NNODES;
  int* end_from = ia + 5*NNODES;
  int* bsum     = ia + 6*NNODES;
  int* bpre     = bsum + 2*NBLK;
  int* pay_to   = bpre + 2*NBLK;
  int* pay_from = pay_to + NEDGES;
  int* rank_to  = pay_from + NEDGES;
  int* rank_from= rank_to + NEDGES;

  const int GB = (NNODES + 63)/64;    // 782
  const int GE = (NEDGES + 255)/256;  // 3125
  const int GN = (NNODES + 15)/16;    // 3125 (16-lane gathers)

  // CSR build: 1 atomic pass + parallel scan + non-atomic place
  hipMemsetAsync(cnt_to, 0, 2*NNODES*sizeof(int), stream);
  k_hist<<<GE,256,0,stream>>>(i_to, i_from, cnt_to, cnt_from, rank_to, rank_from);
  k_scanA<<<2*NBLK,256,0,stream>>>(cnt_to, cnt_from, bsum);
  k_scanB<<<1,256,0,stream>>>(bsum, bpre);
  k_scanC<<<2*NBLK,256,0,stream>>>(cnt_to, cnt_from, bpre, off_to, end_to, off_from, end_from);
  k_place<<<GE,256,0,stream>>>(i_link, i_from, i_to, off_to, off_from,
                               rank_to, rank_from, pay_to, pay_from);

  // weight prepacks + node features
  k_prepw<<<512,512,0,stream>>>(Wi, Wo, Wf, Wu, WgT);
  k_prepw_c<<<128,320,0,stream>>>(Wc, Wcfrag);
  k_prepw_l<<<128,128,0,stream>>>(Wl, Wlfrag);
  k_linkpart<<<50,128,0,stream>>>(emb_link, Wl, bl, linkpart);
  k_ne<<<GB,256,0,stream>>>(i_token, emb_token, Wcfrag, bc, Wlfrag, npart);

  // x gathers -> bf16
  k_gather_xin <<<GN,256,0,stream>>>(off_to,  end_to,  pay_to,  linkpart, npart, xin);
  k_gather_xout<<<GN,256,0,stream>>>(off_from,end_from,pay_from,linkpart, npart, xout);

  // layer 1 fused
  k_gates<2><<<GB,512,0,stream>>>(xin, xout, nullptr, nullptr, WgT,
                                  bi, bo, bf_, bu, c1buf, h1, nullptr);

  // h gathers -> bf16
  k_gather_sum<<<GN,256,0,stream>>>(off_to,  end_to,  pay_to,  h1, hin);
  k_gather_sum<<<GN,256,0,stream>>>(off_from,end_from,pay_from,h1, houtb);

  // layer 2 fused
  k_gates<4><<<GB,512,0,stream>>>(xin, xout, hin, houtb, WgT,
                                  bi, bo, bf_, bu, c1buf, nullptr, out);
}

// Round 8
// 371.274 us; speedup vs baseline: 1.3060x; 1.3060x over previous
//
#include <hip/hip_runtime.h>
#include <math.h>

#define NNODES 50000
#define NEDGES 800000
#define NBLK 196   // ceil(50000/256)
#define GN 3125    // ceil(50000/16)

typedef __attribute__((ext_vector_type(8))) short s16x8;
typedef __attribute__((ext_vector_type(8))) unsigned short u16x8;
typedef __attribute__((ext_vector_type(4))) unsigned short u16x4;
typedef __attribute__((ext_vector_type(4))) float f32x4;

__device__ __forceinline__ float tanh_fast(float x){
  float e = __builtin_amdgcn_exp2f(x*2.885390081777927f);   // e^(2x)
  return 1.0f - 2.0f*__builtin_amdgcn_rcpf(e+1.0f);
}
__device__ __forceinline__ float sig_fast(float x){
  float e = __builtin_amdgcn_exp2f(-1.4426950408889634f*x); // e^(-x)
  return __builtin_amdgcn_rcpf(1.0f+e);
}
__device__ __forceinline__ unsigned short f2b(float f){
  union{float f; unsigned u;} v; v.f = f;
  unsigned r = (v.u + 0x7FFFu + ((v.u>>16)&1u)) >> 16;
  return (unsigned short)r;
}
__device__ __forceinline__ float b2f(unsigned short b){
  union{unsigned u; float f;} v; v.u = ((unsigned)b)<<16; return v.f;
}

// ---------- fused weight prep: WgT / Wcfrag / Wlfrag / linkpart ----------
__global__ __launch_bounds__(512) void k_prep_all(
    const float* __restrict__ Wi, const float* __restrict__ Wo,
    const float* __restrict__ Wf, const float* __restrict__ Wu,
    const float* __restrict__ Wc, const float* __restrict__ Wl,
    const float* __restrict__ emb_link, const float* __restrict__ bl,
    unsigned short* __restrict__ Wfrag, unsigned short* __restrict__ Wcfrag,
    unsigned short* __restrict__ Wlfrag, unsigned short* __restrict__ lp){
  int b = blockIdx.x, t = threadIdx.x;
  if(b < 512){                       // gate weights, n=b, k=t
    int n = b, k = t;
    const float* W = (n<128)? Wi : (n<256)? Wo : (n<384)? Wf : Wu;
    float v = W[(size_t)k*128 + (n&127)];
    int ks = k>>5, kb = (k>>3)&3, j = k&7;
    int nt = n>>4, lm = n&15;
    int l = lm + 16*kb;
    Wfrag[(size_t)(((ks*32 + nt)*64) + l)*8 + j] = f2b(v);
  } else if(b < 640){                // Wc (K padded 300->320), n=b-512, k=t<320
    if(t < 320){
      int n = b-512, k = t;
      float v = (k < 300)? Wc[(size_t)k*128 + n] : 0.f;
      int ks = k>>5, kb = (k>>3)&3, j = k&7;
      int nt = n>>4, lm = n&15;
      int l = lm + 16*kb;
      Wcfrag[(size_t)(((ks*8 + nt)*64) + l)*8 + j] = f2b(v);
    }
  } else if(b < 768){                // Wl bottom 128 rows, n=b-640, k=t<128
    if(t < 128){
      int n = b-640, k = t;
      float v = Wl[(size_t)(64+k)*128 + n];
      int ks = k>>5, kb = (k>>3)&3, j = k&7;
      int nt = n>>4, lm = n&15;
      int l = lm + 16*kb;
      Wlfrag[(size_t)(((ks*8 + nt)*64) + l)*8 + j] = f2b(v);
    }
  } else {                           // linkpart, l=b-768, d=t<128
    if(t < 128){
      int l = b-768, d = t;
      float acc = bl[d];
      #pragma unroll 8
      for(int k=0;k<64;k++) acc += emb_link[l*64+k]*Wl[k*128+d];
      lp[l*128+d] = f2b(acc);
    }
  }
}

// Fused: E1 = tanh(gather(emb_token)@Wc + bc); npart = bf16(E1 @ Wl[64:192])
__global__ __launch_bounds__(256,2) void k_ne(const int* __restrict__ i_token,
      const float* __restrict__ emb_token, const unsigned short* __restrict__ Wcfrag,
      const float* __restrict__ bc, const unsigned short* __restrict__ Wlfrag,
      unsigned short* __restrict__ npart){
  __shared__ unsigned short As[64*36];
  __shared__ unsigned short E1[64*132];
  __shared__ int rowidx[64];
  int t = threadIdx.x;
  int m0 = blockIdx.x*64;
  if(t<64){ int m=m0+t; rowidx[t]=(m<NNODES)? i_token[m]:0; }
  int w=t>>6, l=t&63, lm=l&15, kb=l>>4;
  f32x4 acc[2][4];
  #pragma unroll
  for(int c=0;c<2;c++)
    #pragma unroll
    for(int r=0;r<4;r++) acc[c][r]=(f32x4){0.f,0.f,0.f,0.f};
  int sr=t>>2, sp=t&3;
  __syncthreads();
  const float* srcrow = emb_token + (size_t)rowidx[sr]*300;
  for(int ks=0; ks<10; ks++){
    int k0 = ks*32 + sp*8;
    u16x8 v;
    #pragma unroll
    for(int j=0;j<8;j++){ int k=k0+j; v[j] = (k<300)? f2b(srcrow[k]) : (unsigned short)0; }
    if(ks) __syncthreads();
    *(u16x8*)(As + sr*36 + sp*8) = v;
    __syncthreads();
    s16x8 af[4];
    #pragma unroll
    for(int rt=0;rt<4;rt++) af[rt] = *(const s16x8*)(As + (16*rt+lm)*36 + kb*8);
    #pragma unroll
    for(int c=0;c<2;c++){
      int nt = 2*w + c;
      s16x8 bfr = *(const s16x8*)(Wcfrag + (size_t)((ks*8+nt)*64 + l)*8);
      #pragma unroll
      for(int rt=0;rt<4;rt++)
        acc[c][rt] = __builtin_amdgcn_mfma_f32_16x16x32_bf16(af[rt], bfr, acc[c][rt],0,0,0);
    }
  }
  __syncthreads();
  #pragma unroll
  for(int c=0;c<2;c++){
    int d = 16*(2*w+c) + lm;
    float vb = bc[d];
    #pragma unroll
    for(int rt=0;rt<4;rt++)
      #pragma unroll
      for(int reg=0;reg<4;reg++){
        int r = 16*rt + kb*4 + reg;
        E1[r*132 + d] = f2b(tanh_fast(acc[c][rt][reg]+vb));
      }
  }
  __syncthreads();
  f32x4 acc2[2][4];
  #pragma unroll
  for(int c=0;c<2;c++)
    #pragma unroll
    for(int r=0;r<4;r++) acc2[c][r]=(f32x4){0.f,0.f,0.f,0.f};
  #pragma unroll
  for(int ks=0; ks<4; ks++){
    s16x8 af[4];
    #pragma unroll
    for(int rt=0;rt<4;rt++) af[rt] = *(const s16x8*)(E1 + (16*rt+lm)*132 + ks*32 + kb*8);
    #pragma unroll
    for(int c=0;c<2;c++){
      int nt = 2*w + c;
      s16x8 bfr = *(const s16x8*)(Wlfrag + (size_t)((ks*8+nt)*64 + l)*8);
      #pragma unroll
      for(int rt=0;rt<4;rt++)
        acc2[c][rt] = __builtin_amdgcn_mfma_f32_16x16x32_bf16(af[rt], bfr, acc2[c][rt],0,0,0);
    }
  }
  #pragma unroll
  for(int c=0;c<2;c++){
    int d = 16*(2*w+c) + lm;
    #pragma unroll
    for(int rt=0;rt<4;rt++)
      #pragma unroll
      for(int reg=0;reg<4;reg++){
        int m = m0 + 16*rt + kb*4 + reg;
        if(m < NNODES) npart[(size_t)m*128 + d] = f2b(acc2[c][rt][reg]);
      }
  }
}

// ---------------- CSR build ----------------
__global__ void k_hist(const int* __restrict__ i_to, const int* __restrict__ i_from,
                       int* __restrict__ cnt_to, int* __restrict__ cnt_from,
                       int* __restrict__ rank_to, int* __restrict__ rank_from){
  int e = blockIdx.x*256 + threadIdx.x;
  if(e >= NEDGES) return;
  rank_to[e]   = atomicAdd(&cnt_to[i_to[e]], 1);
  rank_from[e] = atomicAdd(&cnt_from[i_from[e]], 1);
}

__global__ __launch_bounds__(256) void k_scanA(const int* __restrict__ cnt_to,
      const int* __restrict__ cnt_from, int* __restrict__ bsum){
  int b = blockIdx.x; int dir = (b >= NBLK); int bb = dir? b-NBLK : b;
  const int* cnt = dir? cnt_from : cnt_to;
  int t = threadIdx.x;
  int idx = bb*256 + t;
  int c = (idx < NNODES)? cnt[idx] : 0;
  __shared__ int red[256];
  red[t] = c; __syncthreads();
  for(int s=128;s>0;s>>=1){ if(t<s) red[t]+=red[t+s]; __syncthreads(); }
  if(t==0) bsum[b] = red[0];
}

// fused scanB+scanC: each block redundantly scans its direction's 196 block sums
__global__ __launch_bounds__(256) void k_scanBC(const int* __restrict__ bsum,
      const int* __restrict__ cnt_to, const int* __restrict__ cnt_from,
      int* __restrict__ off_to, int* __restrict__ end_to,
      int* __restrict__ off_from, int* __restrict__ end_from){
  int b = blockIdx.x; int dir = (b >= NBLK); int bb = dir? b-NBLK : b;
  const int* cnt = dir? cnt_from : cnt_to;
  int* off = dir? off_from : off_to;
  int* end = dir? end_from : end_to;
  __shared__ int sh[256];
  int t = threadIdx.x;
  sh[t] = (t < NBLK)? bsum[dir*NBLK + t] : 0;
  __syncthreads();
  for(int d=1; d<256; d<<=1){
    int v = (t>=d)? sh[t-d] : 0;
    __syncthreads(); sh[t] += v; __syncthreads();
  }
  int bpre = (bb==0)? 0 : sh[bb-1];
  __syncthreads();
  int idx = bb*256 + t;
  int c = (idx < NNODES)? cnt[idx] : 0;
  sh[t] = c; __syncthreads();
  for(int d=1; d<256; d<<=1){
    int v = (t>=d)? sh[t-d] : 0;
    __syncthreads(); sh[t] += v; __syncthreads();
  }
  if(idx < NNODES){
    int o = bpre + ((t==0)? 0 : sh[t-1]);
    off[idx] = o;
    end[idx] = o + c;
  }
}

__global__ void k_place(const int* __restrict__ i_link, const int* __restrict__ i_from,
                        const int* __restrict__ i_to,
                        const int* __restrict__ off_to, const int* __restrict__ off_from,
                        const int* __restrict__ rank_to, const int* __restrict__ rank_from,
                        int* __restrict__ pay_to, int* __restrict__ pay_from){
  int e = blockIdx.x*256 + threadIdx.x;
  if(e >= NEDGES) return;
  int il = i_link[e], f = i_from[e], tt = i_to[e];
  pay_to[off_to[tt] + rank_to[e]]   = f  | (il<<16);
  pay_from[off_from[f] + rank_from[e]] = tt | (il<<16);
}

// ---------------- gathers (16 lanes per node, u16x8 = 16B per lane) ----------------
// fused x-gathers: first GN blocks = x_in (to-CSR), next GN = x_out (from-CSR)
__global__ __launch_bounds__(256) void k_gather_x(
      const int* __restrict__ off_to, const int* __restrict__ end_to, const int* __restrict__ pay_to,
      const int* __restrict__ off_from, const int* __restrict__ end_from, const int* __restrict__ pay_from,
      const unsigned short* __restrict__ lp, const unsigned short* __restrict__ npart,
      unsigned short* __restrict__ xin, unsigned short* __restrict__ xout){
  int isOut = (blockIdx.x >= GN);
  int bb = isOut? blockIdx.x-GN : blockIdx.x;
  int n = bb*16 + (threadIdx.x>>4);
  if(n >= NNODES) return;
  int c = (threadIdx.x & 15)*8;
  const int* off = isOut? off_from : off_to;
  const int* end = isOut? end_from : end_to;
  const int* pay = isOut? pay_from : pay_to;
  unsigned short* out = isOut? xout : xin;
  float acc[8];
  #pragma unroll
  for(int q=0;q<8;q++) acc[q]=0.f;
  int s = off[n], e = end[n];
  if(isOut){
    u16x8 bb8 = *(const u16x8*)(npart + (size_t)n*128 + c);
    float bf[8];
    #pragma unroll
    for(int q=0;q<8;q++) bf[q]=b2f(bb8[q]);
    for(int j=s;j<e;j++){
      int il = pay[j] >> 16;
      u16x8 a = *(const u16x8*)(lp + il*128 + c);
      #pragma unroll
      for(int q=0;q<8;q++) acc[q] += tanh_fast(b2f(a[q])+bf[q]);
    }
  } else {
    for(int j=s;j<e;j++){
      int p = pay[j];
      int src = p & 0xFFFF, il = p >> 16;
      u16x8 a = *(const u16x8*)(lp + il*128 + c);
      u16x8 b = *(const u16x8*)(npart + (size_t)src*128 + c);
      #pragma unroll
      for(int q=0;q<8;q++) acc[q] += tanh_fast(b2f(a[q])+b2f(b[q]));
    }
  }
  u16x8 o;
  #pragma unroll
  for(int q=0;q<8;q++) o[q]=f2b(acc[q]);
  *(u16x8*)(out + (size_t)n*128 + c) = o;
}

// fused h-gathers: first GN blocks = h_in (to-CSR), next GN = h_out (from-CSR)
__global__ __launch_bounds__(256) void k_gather_h(
      const int* __restrict__ off_to, const int* __restrict__ end_to, const int* __restrict__ pay_to,
      const int* __restrict__ off_from, const int* __restrict__ end_from, const int* __restrict__ pay_from,
      const unsigned short* __restrict__ src, unsigned short* __restrict__ hin,
      unsigned short* __restrict__ hout){
  int isOut = (blockIdx.x >= GN);
  int bb = isOut? blockIdx.x-GN : blockIdx.x;
  int n = bb*16 + (threadIdx.x>>4);
  if(n >= NNODES) return;
  int c = (threadIdx.x & 15)*8;
  const int* off = isOut? off_from : off_to;
  const int* end = isOut? end_from : end_to;
  const int* pay = isOut? pay_from : pay_to;
  unsigned short* out = isOut? hout : hin;
  float acc[8];
  #pragma unroll
  for(int q=0;q<8;q++) acc[q]=0.f;
  int s = off[n], e = end[n];
  for(int j=s;j<e;j++){
    int v = pay[j] & 0xFFFF;
    u16x8 a = *(const u16x8*)(src + (size_t)v*128 + c);
    #pragma unroll
    for(int q=0;q<8;q++) acc[q] += b2f(a[q]);
  }
  u16x8 o;
  #pragma unroll
  for(int q=0;q<8;q++) o[q]=f2b(acc[q]);
  *(u16x8*)(out + (size_t)n*128 + c) = o;
}

// ---------------- fused MFMA gate GEMM + LSTM cell ----------------
// LDS-staged A (pad 36), double-buffered + reg-prefetch: ONE barrier per k-step,
// next-step HBM load in flight across the MFMA cluster (T3-min / T14).
template<int P>
__device__ __forceinline__ const unsigned short* pick(
    const unsigned short* x0, const unsigned short* x1,
    const unsigned short* x2, const unsigned short* x3, int ks){
  if(P==2) return (ks<4)? x0 : x1;
  return (ks<4)? x0 : (ks<8)? x1 : (ks<12)? x2 : x3;
}

template<int P>
__global__ __launch_bounds__(256,2) void k_gates(
    const unsigned short* __restrict__ x0, const unsigned short* __restrict__ x1,
    const unsigned short* __restrict__ x2, const unsigned short* __restrict__ x3,
    const unsigned short* __restrict__ Wfrag,
    const float* __restrict__ bi, const float* __restrict__ bo,
    const float* __restrict__ bfg, const float* __restrict__ bu,
    float* __restrict__ cbuf, unsigned short* __restrict__ h1,
    float* __restrict__ hout)
{
  __shared__ unsigned short As[2][64*36];
  int t = threadIdx.x;
  int m0 = blockIdx.x*64;
  int w = t>>6; int l = t&63;
  int lm = l&15, kb = l>>4;
  f32x4 acc[2][4][4];
  #pragma unroll
  for(int a=0;a<2;a++)
    #pragma unroll
    for(int g=0;g<4;g++)
      #pragma unroll
      for(int r=0;r<4;r++) acc[a][g][r]=(f32x4){0.f,0.f,0.f,0.f};
  int sr = t>>2, sp = t&3;
  int sm = m0 + sr; if(sm >= NNODES) sm = NNODES-1;
  size_t soff = (size_t)sm*128 + sp*8;
  const int KSTEPS = P*4;
  // prologue: stage ks=0, prefetch ks=1 to reg
  u16x8 v0 = *(const u16x8*)(pick<P>(x0,x1,x2,x3,0) + soff + 0);
  *(u16x8*)(As[0] + sr*36 + sp*8) = v0;
  u16x8 vn = *(const u16x8*)(pick<P>(x0,x1,x2,x3,1) + soff + 32);
  __syncthreads();
  #pragma unroll
  for(int ks=0; ks<KSTEPS; ks++){
    int cur = ks&1;
    if(ks+1 < KSTEPS) *(u16x8*)(As[cur^1] + sr*36 + sp*8) = vn;   // stage next
    if(ks+2 < KSTEPS)                                             // prefetch next-next
      vn = *(const u16x8*)(pick<P>(x0,x1,x2,x3,ks+2) + soff + ((ks+2)&3)*32);
    s16x8 af[4];
    #pragma unroll
    for(int rt=0; rt<4; rt++)
      af[rt] = *(const s16x8*)(As[cur] + (16*rt+lm)*36 + kb*8);
    #pragma unroll
    for(int c=0;c<2;c++){
      #pragma unroll
      for(int g=0;g<4;g++){
        int nt = 8*g + 2*w + c;
        s16x8 bfr = *(const s16x8*)(Wfrag + (size_t)((ks*32 + nt)*64 + l)*8);
        #pragma unroll
        for(int rt=0; rt<4; rt++)
          acc[c][g][rt] = __builtin_amdgcn_mfma_f32_16x16x32_bf16(af[rt], bfr, acc[c][g][rt], 0,0,0);
      }
    }
    __syncthreads();   // next-iter writes to As[cur] are safe after this
  }
  #pragma unroll
  for(int c=0;c<2;c++){
    int d = 16*(2*w+c) + lm;
    float vbi = bi[d], vbo = bo[d], vbu = bu[d];
    float vbf = (P==4)? bfg[d] : 0.f;
    #pragma unroll
    for(int rt=0; rt<4; rt++){
      #pragma unroll
      for(int reg=0; reg<4; reg++){
        int m = m0 + 16*rt + kb*4 + reg;
        if(m < NNODES){
          size_t o = (size_t)m*128 + d;
          float pi = acc[c][0][rt][reg] + vbi;
          float po = acc[c][1][rt][reg] + vbo;
          float pu = acc[c][3][rt][reg] + vbu;
          if(P==2){
            float c1v = sig_fast(pi)*tanh_fast(pu);
            float hv  = sig_fast(po)*tanh_fast(c1v);
            cbuf[o] = c1v;
            h1[o] = f2b(hv);
          } else {
            float pf = acc[c][2][rt][reg] + vbf;
            float c2 = sig_fast(pf)*cbuf[o] + sig_fast(pi)*tanh_fast(pu);
            hout[o] = sig_fast(po)*tanh_fast(c2);
          }
        }
      }
    }
  }
}

extern "C" void kernel_launch(void* const* d_in, const int* in_sizes, int n_in,
                              void* d_out, int out_size, void* d_ws, size_t ws_size,
                              hipStream_t stream){
  const int*   i_token  = (const int*)d_in[0];
  const int*   i_link   = (const int*)d_in[1];
  const int*   i_from   = (const int*)d_in[2];
  const int*   i_to     = (const int*)d_in[3];
  const float* emb_token= (const float*)d_in[4];
  const float* emb_link = (const float*)d_in[5];
  const float* Wc = (const float*)d_in[6];  const float* bc = (const float*)d_in[7];
  const float* Wl = (const float*)d_in[8];  const float* bl = (const float*)d_in[9];
  const float* Wi = (const float*)d_in[10]; const float* bi = (const float*)d_in[11];
  const float* Wo = (const float*)d_in[12]; const float* bo = (const float*)d_in[13];
  const float* Wf = (const float*)d_in[14]; const float* bf_ = (const float*)d_in[15];
  const float* Wu = (const float*)d_in[16]; const float* bu = (const float*)d_in[17];
  float* out = (float*)d_out;

  const size_t NB = (size_t)NNODES*128;
  float* c1buf  = (float*)d_ws;
  unsigned short* npart = (unsigned short*)(c1buf + NB);
  unsigned short* xin   = npart + NB;
  unsigned short* xout  = xin + NB;
  unsigned short* hin   = xout + NB;
  unsigned short* houtb = hin + NB;
  unsigned short* h1    = houtb + NB;
  unsigned short* WgT   = h1 + NB;
  unsigned short* Wcfrag = WgT + 512*512;
  unsigned short* Wlfrag = Wcfrag + 320*128;
  unsigned short* linkpart = Wlfrag + 128*128;
  int* ia = (int*)(linkpart + 50*128);
  int* cnt_to   = ia + 0*NNODES;
  int* cnt_from = ia + 1*NNODES;
  int* off_to   = ia + 2*NNODES;
  int* end_to   = ia + 3*NNODES;
  int* off_from = ia + 4*NNODES;
  int* end_from = ia + 5*NNODES;
  int* bsum     = ia + 6*NNODES;
  int* pay_to   = bsum + 2*NBLK;
  int* pay_from = pay_to + NEDGES;
  int* rank_to  = pay_from + NEDGES;
  int* rank_from= rank_to + NEDGES;

  const int GB = (NNODES + 63)/64;    // 782
  const int GE = (NEDGES + 255)/256;  // 3125

  // CSR build: 1 atomic pass + parallel scan + non-atomic place
  hipMemsetAsync(cnt_to, 0, 2*NNODES*sizeof(int), stream);
  k_hist<<<GE,256,0,stream>>>(i_to, i_from, cnt_to, cnt_from, rank_to, rank_from);
  k_scanA<<<2*NBLK,256,0,stream>>>(cnt_to, cnt_from, bsum);
  k_scanBC<<<2*NBLK,256,0,stream>>>(bsum, cnt_to, cnt_from, off_to, end_to, off_from, end_from);
  k_place<<<GE,256,0,stream>>>(i_link, i_from, i_to, off_to, off_from,
                               rank_to, rank_from, pay_to, pay_from);

  // weight prepacks + node features
  k_prep_all<<<818,512,0,stream>>>(Wi, Wo, Wf, Wu, Wc, Wl, emb_link, bl,
                                   WgT, Wcfrag, Wlfrag, linkpart);
  k_ne<<<GB,256,0,stream>>>(i_token, emb_token, Wcfrag, bc, Wlfrag, npart);

  // x gathers -> bf16 (fused in/out)
  k_gather_x<<<2*GN,256,0,stream>>>(off_to, end_to, pay_to, off_from, end_from, pay_from,
                                    linkpart, npart, xin, xout);

  // layer 1 fused
  k_gates<2><<<GB,256,0,stream>>>(xin, xout, nullptr, nullptr, WgT,
                                  bi, bo, bf_, bu, c1buf, h1, nullptr);

  // h gathers -> bf16 (fused in/out)
  k_gather_h<<<2*GN,256,0,stream>>>(off_to, end_to, pay_to, off_from, end_from, pay_from,
                                    h1, hin, houtb);

  // layer 2 fused
  k_gates<4><<<GB,256,0,stream>>>(xin, xout, hin, houtb, WgT,
                                  bi, bo, bf_, bu, c1buf, nullptr, out);
}